// Round 9
// baseline (392.821 us; speedup 1.0000x reference)
//
#include <hip/hip_runtime.h>
#include <hip/hip_fp16.h>
#include <math.h>

#define NN 50000
#define NE 600000
#define IN_DIM 7
#define SCAN_B ((NN + 255) / 256)   // 196 blocks

// AB is stored pre-scaled by -2*log2(e) so tanh(a+b) = 2*rcp(1+exp2(a'+b')) - 1
#define NEG2LOG2E -2.8853900817779268f

typedef _Float16 half8 __attribute__((ext_vector_type(8)));
typedef short short8 __attribute__((ext_vector_type(8)));
typedef float f32x4  __attribute__((ext_vector_type(4)));
typedef unsigned int uint;

#if __has_builtin(__builtin_amdgcn_exp2f)
#define EXP2F(x) __builtin_amdgcn_exp2f(x)
#else
#define EXP2F(x) __expf(0.6931471805599453f * (x))
#endif

// issue a clamped batch gather for edges [SB, SB+4)
#define LOAD_BATCH(D, SB)                                     \
    {                                                         \
        int ss = (SB) + g;                                    \
        int sc = (ss < s1) ? ss : (s1 - 1);                   \
        bv[D] = AB4[(size_t)(uint)ssrc[sc] + qoff];           \
    }
// consume batch D covering edges [SB, SB+4)
#define CONSUME(D, SB)                                        \
    if ((SB) + g < s1) {                                      \
        uint bh[4] = {bv[D].x, bv[D].y, bv[D].z, bv[D].w};    \
        _Pragma("unroll")                                     \
        for (int k = 0; k < 4; k++) {                         \
            __half2 ua = *reinterpret_cast<__half2*>(&ah[k]); \
            __half2 ub = *reinterpret_cast<__half2*>(&bh[k]); \
            __half2 u2 = __hadd2(ua, ub);                     \
            float2 uf = __half22float2(u2);                   \
            float e0 = EXP2F(uf.x);                           \
            float e1 = EXP2F(uf.y);                           \
            acc[2 * k + 0] += __builtin_amdgcn_rcpf(1.f + e0);\
            acc[2 * k + 1] += __builtin_amdgcn_rcpf(1.f + e1);\
        }                                                     \
    }

// run the whole pipelined edge loop for node i; leaves acc[8] filled
#define AGG_LOOP()                                            \
    if (s0 < s1) {                                            \
        LOAD_BATCH(0, s0)                                     \
        LOAD_BATCH(1, s0 + 4)                                 \
        LOAD_BATCH(2, s0 + 8)                                 \
        LOAD_BATCH(3, s0 + 12)                                \
        int s = s0;                                           \
        for (; s + 16 < s1; s += 16) {                        \
            CONSUME(0, s)      LOAD_BATCH(0, s + 16)          \
            CONSUME(1, s + 4)  LOAD_BATCH(1, s + 20)          \
            CONSUME(2, s + 8)  LOAD_BATCH(2, s + 24)          \
            CONSUME(3, s + 12) LOAD_BATCH(3, s + 28)          \
        }                                                     \
        CONSUME(0, s)                                         \
        CONSUME(1, s + 4)                                     \
        CONSUME(2, s + 8)                                     \
        CONSUME(3, s + 12)                                    \
    }

// ---------------- CSR build ----------------

__global__ void k_zero_int(int* __restrict__ p, int n) {
    int i = blockIdx.x * blockDim.x + threadIdx.x;
    if (i < n) p[i] = 0;
}

__global__ void k_count(const int* __restrict__ ei, int* __restrict__ deg) {
    int e = blockIdx.x * blockDim.x + threadIdx.x;
    if (e < NE) atomicAdd(&deg[ei[NE + e]], 1);
}

__global__ __launch_bounds__(256) void k_scan1(const int* __restrict__ deg,
                                               int* __restrict__ off,
                                               int* __restrict__ part) {
    __shared__ int s[256];
    int i = blockIdx.x * 256 + threadIdx.x;
    int v = (i < NN) ? deg[i] : 0;
    s[threadIdx.x] = v;
    __syncthreads();
    #pragma unroll
    for (int o = 1; o < 256; o <<= 1) {
        int t = (threadIdx.x >= o) ? s[threadIdx.x - o] : 0;
        __syncthreads();
        s[threadIdx.x] += t;
        __syncthreads();
    }
    if (i < NN) off[i] = s[threadIdx.x] - v;
    if (threadIdx.x == 255) part[blockIdx.x] = s[255];
}

// scan3 now does its own prefix over the 196 partials (scan2 eliminated)
__global__ __launch_bounds__(256) void k_scan3(int* __restrict__ off,
                                               const int* __restrict__ part,
                                               int* __restrict__ cur) {
    __shared__ int sp[SCAN_B];
    int t = threadIdx.x;
    if (t < SCAN_B) sp[t] = part[t];
    __syncthreads();
    int bid = blockIdx.x;
    int psum = 0;
    for (int j = 0; j < bid; j++) psum += sp[j];
    int i = bid * 256 + t;
    if (i < NN) {
        int v = off[i] + psum;
        off[i] = v;
        cur[i] = v;
    }
    if (bid == 0 && t == 0) off[NN] = NE;   // grand total is a constant
}

// ssrc stores src*32 (uint4-stride units) so agg's gather address chain is add-only
__global__ void k_scatter(const int* __restrict__ ei, int* __restrict__ cur,
                          int* __restrict__ ssrc) {
    int e = blockIdx.x * blockDim.x + threadIdx.x;
    if (e < NE) {
        int s = ei[e];
        int d = ei[NE + e];
        int pos = atomicAdd(&cur[d], 1);
        ssrc[pos] = s * 32;
    }
}

// ---------------- one-shot weight prep ----------------

__global__ __launch_bounds__(128) void k_prep(const float* __restrict__ W1_0,
                                              const float* __restrict__ W2_0,
                                              const float* __restrict__ b2_0,
                                              const float* __restrict__ W1s,
                                              const float* __restrict__ b1s,
                                              const float* __restrict__ W2s,
                                              const float* __restrict__ b2s,
                                              const float* __restrict__ Wo,
                                              float* __restrict__ Wc0,
                                              _Float16* __restrict__ Wt_all,
                                              float* __restrict__ dvec_all,
                                              float* __restrict__ bcat_all,
                                              float* __restrict__ Wf,
                                              float* __restrict__ bfh2) {
    int b = blockIdx.x;
    int t = threadIdx.x;
    if (b < 768) {
        int g = b >> 8, c = b & 255;
        const float* W1g = W1s + (size_t)g * 256 * 128;
        const float* b1g = b1s + (size_t)g * 128;
        const float* W2p = (g == 0) ? W2_0 : W2s + (size_t)(g - 1) * 128 * 128;
        const float* b2p = (g == 0) ? b2_0 : b2s + (size_t)(g - 1) * 128;
        __shared__ float wc[128];
        int m = t;
        float v;
        if (c < 128) v = W1g[m * 128 + c] - W1g[(m + 128) * 128 + c];
        else         v = W1g[(m + 128) * 128 + (c - 128)];
        wc[m] = v;
        __syncthreads();
        int k = t;
        float acc = 0.f;
        #pragma unroll 8
        for (int mm = 0; mm < 128; mm++) acc += W2p[k * 128 + mm] * wc[mm];
        Wt_all[(size_t)g * 32768 + c * 128 + k] = (_Float16)acc;
        if (t == 0) {
            float dacc = 0.f;
            for (int mm = 0; mm < 128; mm++) dacc += b2p[mm] * wc[mm];
            dvec_all[g * 256 + c] = dacc;
            bcat_all[g * 256 + c] = (c < 128) ? b1g[c] : 0.f;
        }
    } else if (b == 768) {
        for (int idx = t; idx < IN_DIM * 256; idx += 128) {
            int k = idx >> 8, c = idx & 255;
            float v;
            if (c < 128) v = W1_0[k * 128 + c] - W1_0[(k + IN_DIM) * 128 + c];
            else         v = W1_0[(k + IN_DIM) * 128 + (c - 128)];
            Wc0[idx] = v;
        }
    } else {
        const float* W2l = W2s + (size_t)2 * 128 * 128;
        const float* b2l = b2s + (size_t)2 * 128;
        int k = t;
        #pragma unroll
        for (int r = 0; r < 3; r++) {
            float acc = 0.f;
            for (int m = 0; m < 128; m++) acc += W2l[k * 128 + m] * Wo[m * 3 + r];
            Wf[k * 3 + r] = acc;
        }
        __syncthreads();
        if (k < 3) {
            float acc = 0.f;
            for (int m = 0; m < 128; m++) acc += b2l[m] * Wo[m * 3 + k];
            float wfsum = 0.f;
            for (int m = 0; m < 128; m++) wfsum += Wf[m * 3 + k];
            bfh2[k] = acc - wfsum;
        }
    }
}

// ---------------- layer-0: AB = (-2log2e)*(x @ Wc0 + b1cat) (fp16 out) ----------------

__global__ __launch_bounds__(256) void k_l0(const float* __restrict__ x,
                                            const float* __restrict__ Wc,
                                            const float* __restrict__ b1,
                                            _Float16* __restrict__ AB) {
    int i = blockIdx.x;
    int c = threadIdx.x;
    __shared__ float xs[IN_DIM];
    if (threadIdx.x < IN_DIM) xs[threadIdx.x] = x[i * IN_DIM + threadIdx.x];
    __syncthreads();
    float acc = (c < 128) ? b1[c] : 0.f;
    #pragma unroll
    for (int k = 0; k < IN_DIM; k++) acc += xs[k] * Wc[k * 256 + c];
    AB[i * 256 + c] = (_Float16)(NEG2LOG2E * acc);
}

// ---------------- FUSED aggregate + GEMM ----------------
// Block = 16 nodes, 4 waves. Phase 1: each wave aggregates 4 nodes (one at a
// time; 16 lanes/edge-group, 4 groups, 4-deep batch prefetch), T row (=2*acc-deg)
// goes to LDS as fp16. Phase 2: 16x256 MFMA tile reading A-frags from LDS,
// B-frags (fused weight, col-major) from global; epilogue writes next AB
// (pre-scaled) straight to the ping-pong buffer. T never touches HBM.

__global__ __launch_bounds__(256) void k_agg_gemm(const _Float16* __restrict__ ABin,
                                                  const int* __restrict__ off,
                                                  const int* __restrict__ ssrc,
                                                  const _Float16* __restrict__ Wt,
                                                  const float* __restrict__ dvec,
                                                  const float* __restrict__ bcat,
                                                  _Float16* __restrict__ ABout) {
    __shared__ short Tl[16 * 136];   // +8 shorts pad per row
    __shared__ float degl[16];
    int t = threadIdx.x;
    int lane = t & 63;
    int wv = t >> 6;
    int q = lane & 15;               // channel octet / (phase 2) col-in-tile
    int g = lane >> 4;               // edge group / (phase 2) quad
    int base = blockIdx.x * 16;      // NN = 50000 = 3125 * 16, exact
    const uint4* AB4 = (const uint4*)ABin;
    int qoff = 16 + q;               // uint4 offset of B half-row

    // ---- phase 1: aggregate 4 nodes per wave ----
    for (int it = 0; it < 4; it++) {
        int row = wv * 4 + it;
        int i = base + row;
        uint4 av = AB4[(size_t)i * 32 + q];
        uint ah[4] = {av.x, av.y, av.z, av.w};
        int s0 = off[i], s1 = off[i + 1];
        float acc[8];
        #pragma unroll
        for (int k = 0; k < 8; k++) acc[k] = 0.f;
        uint4 bv[4];
        AGG_LOOP()
        #pragma unroll
        for (int k = 0; k < 8; k++) {
            acc[k] += __shfl_xor(acc[k], 16);
            acc[k] += __shfl_xor(acc[k], 32);
        }
        float degf = (float)(s1 - s0);
        if (lane < 16) {
            uint4 pv;
            uint* pu = reinterpret_cast<uint*>(&pv);
            #pragma unroll
            for (int k = 0; k < 4; k++) {
                __half2 p = __float22half2_rn(make_float2(
                    2.f * acc[2 * k + 0] - degf, 2.f * acc[2 * k + 1] - degf));
                pu[k] = *reinterpret_cast<uint*>(&p);
            }
            *(uint4*)&Tl[row * 136 + q * 8] = pv;
        }
        if (lane == 0) degl[row] = degf;
    }
    __syncthreads();

    // ---- phase 2: 16x256 GEMM tile ----
    const short* Ws = (const short*)Wt;
    half8 a[4];
    #pragma unroll
    for (int ks = 0; ks < 4; ks++) {
        short8 s8 = *(const short8*)&Tl[q * 136 + ks * 32 + g * 8];
        a[ks] = __builtin_bit_cast(half8, s8);
    }
    int c0 = wv * 64;
    #pragma unroll
    for (int ct = 0; ct < 4; ct++) {
        int ccol = c0 + ct * 16 + q;
        half8 b[4];
        #pragma unroll
        for (int ks = 0; ks < 4; ks++) {
            short8 s8 = *(const short8*)&Ws[ccol * 128 + ks * 32 + g * 8];
            b[ks] = __builtin_bit_cast(half8, s8);
        }
        float bc = bcat[ccol], dv = dvec[ccol];
        f32x4 acc2 = {0.f, 0.f, 0.f, 0.f};
        #pragma unroll
        for (int ks = 0; ks < 4; ks++)
            acc2 = __builtin_amdgcn_mfma_f32_16x16x32_f16(a[ks], b[ks], acc2, 0, 0, 0);
        #pragma unroll
        for (int r = 0; r < 4; r++) {
            int row = g * 4 + r;
            float v = acc2[r] + degl[row] * dv + bc;
            ABout[(size_t)(base + row) * 256 + ccol] = (_Float16)(NEG2LOG2E * v);
        }
    }
}

// ---------------- final aggregate + head ----------------

__global__ __launch_bounds__(256) void k_agg_head(const _Float16* __restrict__ AB,
                                                  const int* __restrict__ off,
                                                  const int* __restrict__ ssrc,
                                                  const float* __restrict__ Wf,
                                                  const float* __restrict__ bfh2,
                                                  const float* __restrict__ bo,
                                                  float* __restrict__ out) {
    int t = threadIdx.x;
    int i = blockIdx.x * 4 + (t >> 6);   // one wave per node
    int lane = t & 63;
    int q = lane & 15;
    int g = lane >> 4;
    const uint4* AB4 = (const uint4*)AB;
    int qoff = 16 + q;

    uint4 av = AB4[(size_t)i * 32 + q];
    uint ah[4] = {av.x, av.y, av.z, av.w};
    int s0 = off[i], s1 = off[i + 1];
    float acc[8];
    #pragma unroll
    for (int k = 0; k < 8; k++) acc[k] = 0.f;
    uint4 bv[4];
    AGG_LOOP()

    int ch = 8 * q;
    float p0 = 0.f, p1 = 0.f, p2 = 0.f;
    #pragma unroll
    for (int k = 0; k < 8; k++) {
        float v = acc[k];
        p0 += v * Wf[(ch + k) * 3 + 0];
        p1 += v * Wf[(ch + k) * 3 + 1];
        p2 += v * Wf[(ch + k) * 3 + 2];
    }
    #pragma unroll
    for (int o = 32; o > 0; o >>= 1) {
        p0 += __shfl_down(p0, o);
        p1 += __shfl_down(p1, o);
        p2 += __shfl_down(p2, o);
    }
    if (lane == 0) {
        float degf = (float)(s1 - s0);
        out[i * 3 + 0] = 2.f * p0 + degf * bfh2[0] + bo[0];
        out[i * 3 + 1] = 2.f * p1 + degf * bfh2[1] + bo[1];
        out[i * 3 + 2] = 2.f * p2 + degf * bfh2[2] + bo[2];
    }
}

// ---------------- host ----------------

extern "C" void kernel_launch(void* const* d_in, const int* in_sizes, int n_in,
                              void* d_out, int out_size, void* d_ws, size_t ws_size,
                              hipStream_t stream) {
    const float* x    = (const float*)d_in[0];
    const int*   ei   = (const int*)d_in[1];
    const float* W1_0 = (const float*)d_in[2];
    const float* b1_0 = (const float*)d_in[3];
    const float* W2_0 = (const float*)d_in[4];
    const float* b2_0 = (const float*)d_in[5];
    const float* W1s  = (const float*)d_in[6];
    const float* b1s  = (const float*)d_in[7];
    const float* W2s  = (const float*)d_in[8];
    const float* b2s  = (const float*)d_in[9];
    const float* Wo   = (const float*)d_in[10];
    const float* bo   = (const float*)d_in[11];
    float* out = (float*)d_out;

    char* w = (char*)d_ws;
    _Float16* ABa = (_Float16*)w;                         w += (size_t)NN * 256 * 2;   // 25.6 MB
    _Float16* ABb = (_Float16*)w;                         w += (size_t)NN * 256 * 2;   // 25.6 MB
    float* Wc0  = (float*)w;                              w += IN_DIM * 256 * 4;
    _Float16* Wt_all = (_Float16*)w;                      w += 3 * 256 * 128 * 2;
    float* dvec = (float*)w;                              w += 3 * 256 * 4;
    float* bcat = (float*)w;                              w += 3 * 256 * 4;
    float* Wf   = (float*)w;                              w += 2048;
    float* bfh2 = (float*)w;                              w += 256;
    int* deg    = (int*)w;                                w += (size_t)NN * 4;
    int* off    = (int*)w;                                w += (size_t)(NN + 4) * 4;
    int* cur    = (int*)w;                                w += (size_t)NN * 4;
    int* ssrc   = (int*)w;                                w += (size_t)NE * 4;
    int* part   = (int*)w;                                w += 1024;

    const int B256 = 256;
    int gN = (NN + B256 - 1) / B256;
    int gE = (NE + B256 - 1) / B256;
    int gFused = NN / 16;   // 3125
    int gHead  = NN / 4;    // 12500

    // ---- CSR by dst (5 launches) ----
    k_zero_int<<<gN, B256, 0, stream>>>(deg, NN);
    k_count<<<gE, B256, 0, stream>>>(ei, deg);
    k_scan1<<<SCAN_B, B256, 0, stream>>>(deg, off, part);
    k_scan3<<<SCAN_B, B256, 0, stream>>>(off, part, cur);
    k_scatter<<<gE, B256, 0, stream>>>(ei, cur, ssrc);

    // ---- all weight prep in one launch ----
    k_prep<<<770, 128, 0, stream>>>(W1_0, W2_0, b2_0, W1s, b1s, W2s, b2s, Wo,
                                    Wc0, Wt_all, dvec, bcat, Wf, bfh2);

    // ---- layer 0 ----
    k_l0<<<NN, 256, 0, stream>>>(x, Wc0, b1_0, ABa);

    // ---- fused agg+gemm transitions (ping-pong AB) ----
    k_agg_gemm<<<gFused, B256, 0, stream>>>(ABa, off, ssrc, Wt_all,
                                            dvec, bcat, ABb);
    k_agg_gemm<<<gFused, B256, 0, stream>>>(ABb, off, ssrc, Wt_all + 32768,
                                            dvec + 256, bcat + 256, ABa);
    k_agg_gemm<<<gFused, B256, 0, stream>>>(ABa, off, ssrc, Wt_all + 65536,
                                            dvec + 512, bcat + 512, ABb);

    // ---- final aggregate + head ----
    k_agg_head<<<gHead, B256, 0, stream>>>(ABb, off, ssrc, Wf, bfh2, bo, out);
}